// Round 14
// baseline (346.696 us; speedup 1.0000x reference)
//
#include <hip/hip_runtime.h>

static __device__ __forceinline__ float silu_f(float v) {
    return v / (1.0f + __expf(-v));
}
// bf16 pack/unpack (RNE)
static __device__ __forceinline__ unsigned short f2bf(float f) {
    unsigned int u = __float_as_uint(f);
    u = (u + 0x7FFFu + ((u >> 16) & 1u)) >> 16;
    return (unsigned short)u;
}
static __device__ __forceinline__ float bf2f(unsigned short h) {
    return __uint_as_float(((unsigned int)h) << 16);
}

// ---------------- bucketed CSR build ----------------

extern "C" __global__ __launch_bounds__(256) void k_bhist(
    const int* __restrict__ dst, int* __restrict__ bcount, int E, int nbkt, int shift)
{
    __shared__ int lh[512];
    int t = threadIdx.x;
    for (int i = t; i < 512; i += 256) lh[i] = 0;
    __syncthreads();
    int e0 = blockIdx.x * 8192;
    #pragma unroll 4
    for (int i = 0; i < 32; i++) {
        int e = e0 + t + i * 256;
        if (e < E) atomicAdd(&lh[dst[e] >> shift], 1);
    }
    __syncthreads();
    for (int b = t; b < nbkt; b += 256)
        if (lh[b]) atomicAdd(&bcount[b], lh[b]);
}

extern "C" __global__ __launch_bounds__(512) void k_bscan(
    const int* __restrict__ bcount, int* __restrict__ boff, int* __restrict__ bcursor, int nbkt)
{
    __shared__ int sc[512];
    int t = threadIdx.x;
    int v = (t < nbkt) ? bcount[t] : 0;
    sc[t] = v;
    __syncthreads();
    for (int off = 1; off < 512; off <<= 1) {
        int add = (t >= off) ? sc[t - off] : 0;
        __syncthreads();
        sc[t] += add;
        __syncthreads();
    }
    int excl = sc[t] - v;
    if (t < nbkt) { boff[t] = excl; bcursor[t] = excl; }
    if (t == nbkt - 1) boff[nbkt] = excl + v;
}

extern "C" __global__ __launch_bounds__(256) void k_bscatter(
    const int* __restrict__ src, const int* __restrict__ dst, int* __restrict__ bcursor,
    int2* __restrict__ ebuf, int E, int nbkt, int shift)
{
    __shared__ int lh[512];
    __shared__ int lbase[512];
    int t = threadIdx.x;
    for (int i = t; i < 512; i += 256) lh[i] = 0;
    __syncthreads();
    int e0 = blockIdx.x * 8192;
    #pragma unroll 4
    for (int i = 0; i < 32; i++) {
        int e = e0 + t + i * 256;
        if (e < E) atomicAdd(&lh[dst[e] >> shift], 1);
    }
    __syncthreads();
    for (int b = t; b < nbkt; b += 256)
        lbase[b] = lh[b] ? atomicAdd(&bcursor[b], lh[b]) : 0;
    __syncthreads();
    #pragma unroll 4
    for (int i = 0; i < 32; i++) {
        int e = e0 + t + i * 256;
        if (e < E) {
            int d = dst[e];
            int p = atomicAdd(&lbase[d >> shift], 1);
            ebuf[p] = make_int2(src[e], d);
        }
    }
}

// fused: per-bucket deg/dinv/rowstart + CSR fill (ebuf window stays L2-hot)
extern "C" __global__ __launch_bounds__(256) void k_bcsr(
    const int2* __restrict__ ebuf, const int* __restrict__ boff,
    int* __restrict__ deg, float* __restrict__ dinv, int* __restrict__ rowstart,
    int* __restrict__ csr, int shift, int N)
{
    int b = blockIdx.x;
    int W = 1 << shift;
    __shared__ int lcur[4096];
    __shared__ int sc[256];
    int t = threadIdx.x;
    for (int i = t; i < W; i += 256) lcur[i] = 0;
    __syncthreads();
    int s = boff[b], e_ = boff[b + 1];
    for (int e = s + t; e < e_; e += 256)
        atomicAdd(&lcur[ebuf[e].y - (b << shift)], 1);
    __syncthreads();

    int c = W >> 8;
    int base = t * c;
    int mysum = 0;
    for (int i = 0; i < c; i++) mysum += lcur[base + i];
    sc[t] = mysum;
    __syncthreads();
    int mine = mysum;
    for (int off = 1; off < 256; off <<= 1) {
        int add = (t >= off) ? sc[t - off] : 0;
        __syncthreads();
        sc[t] += add;
        __syncthreads();
    }
    int run = sc[t] - mine + s;
    int nbase = b << shift;
    for (int i = 0; i < c; i++) {
        int d = lcur[base + i];
        int node = nbase + base + i;
        if (node < N) {
            rowstart[node] = run;
            deg[node] = d;
            dinv[node] = rsqrtf((float)(d + 1));
        }
        lcur[base + i] = run;       // becomes absolute fill cursor
        run += d;
    }
    __syncthreads();
    for (int e = s + t; e < e_; e += 256) {
        int2 p = ebuf[e];
        int pos = atomicAdd(&lcur[p.y - (b << shift)], 1);
        csr[pos] = p.x;
    }
}

// ---------------- gemm1: h0s(bf16) = (x@W1)*dinv ; r1 = silu(x@Wr1+br1) ----------------
// R11 geometry (128 rows/block, 512 thr, 16-col wave slices, 2 rows/lane), but
// W now loaded via per-lane VMEM (wv kept DIVERGENT -> no s_load promotion).
// Wave-uniform addresses coalesce to L1 broadcast; W waits go on vmcnt while
// x waits stay on precise DS lgkmcnt -> both pipelines run deep.
extern "C" __global__ __launch_bounds__(512) void k_gemm1(
    const float* __restrict__ x, const float* __restrict__ W1, const float* __restrict__ Wr1,
    const float* __restrict__ br1, const float* __restrict__ dinv,
    unsigned short* __restrict__ h0s, float* __restrict__ r1, int n)
{
    __shared__ float xs[128 * 36];
    int t = threadIdx.x;
    int lane = t & 63;
    int wv = t >> 6;                       // intentionally NOT readfirstlane: keep divergent
    const float* Wp = (wv < 4) ? W1 : Wr1; // per-lane pointer -> VMEM broadcast loads
    const int c0 = (wv & 3) * 16;
    int r0 = blockIdx.x * 128;

    float acc0[16] = {}, acc1[16] = {};
    float4 px[2];

    #pragma unroll
    for (int i = 0; i < 2; i++) {          // chunk-0 prefetch (1024 f4 / 512 thr)
        int u = t + i * 512;
        int rr = u >> 3, kq = u & 7;
        px[i] = make_float4(0.f, 0.f, 0.f, 0.f);
        if (r0 + rr < n) px[i] = *(const float4*)&x[(size_t)(r0 + rr) * 128 + kq * 4];
    }

    for (int kk = 0; kk < 128; kk += 32) {
        if (kk) __syncthreads();
        #pragma unroll
        for (int i = 0; i < 2; i++) {
            int u = t + i * 512;
            int rr = u >> 3, kq = u & 7;
            *(float4*)&xs[rr * 36 + kq * 4] = px[i];
        }
        __syncthreads();
        if (kk < 96) {                     // prefetch next x chunk under FMA loop
            int kn = kk + 32;
            #pragma unroll
            for (int i = 0; i < 2; i++) {
                int u = t + i * 512;
                int rr = u >> 3, kq = u & 7;
                px[i] = make_float4(0.f, 0.f, 0.f, 0.f);
                if (r0 + rr < n) px[i] = *(const float4*)&x[(size_t)(r0 + rr) * 128 + kn + kq * 4];
            }
        }
        #pragma unroll
        for (int kb = 0; kb < 8; kb++) {   // 4 k's per kb
            float4 xa = *(const float4*)&xs[lane * 36 + kb * 4];
            float4 xb = *(const float4*)&xs[(lane + 64) * 36 + kb * 4];
            float xv0[4] = {xa.x, xa.y, xa.z, xa.w};
            float xv1[4] = {xb.x, xb.y, xb.z, xb.w};
            #pragma unroll
            for (int kq = 0; kq < 4; kq++) {
                const float* wrow = &Wp[(size_t)(kk + kb * 4 + kq) * 64 + c0];
                #pragma unroll
                for (int j = 0; j < 4; j++) {
                    float4 w4 = *(const float4*)&wrow[j * 4];   // VMEM broadcast (vmcnt)
                    acc0[j*4+0] += xv0[kq] * w4.x; acc1[j*4+0] += xv1[kq] * w4.x;
                    acc0[j*4+1] += xv0[kq] * w4.y; acc1[j*4+1] += xv1[kq] * w4.y;
                    acc0[j*4+2] += xv0[kq] * w4.z; acc1[j*4+2] += xv1[kq] * w4.z;
                    acc0[j*4+3] += xv0[kq] * w4.w; acc1[j*4+3] += xv1[kq] * w4.w;
                }
            }
        }
    }

    #pragma unroll
    for (int half = 0; half < 2; half++) {
        int row = r0 + half * 64 + lane;
        if (row >= n) continue;
        const float* a = half ? acc1 : acc0;
        if (wv < 4) {                      // h0s (bf16) cols c0..c0+15
            float dv = dinv[row];
            uint4 o0, o1;
            unsigned int* po = &o0.x;
            #pragma unroll
            for (int q = 0; q < 8; q++) {
                unsigned int lo = f2bf(a[q*2+0] * dv);
                unsigned int hi = f2bf(a[q*2+1] * dv);
                po[q] = lo | (hi << 16);
            }
            uint4* dst0 = (uint4*)&h0s[(size_t)row * 64 + c0];
            dst0[0] = o0; dst0[1] = o1;
        } else {                           // r1 cols c0..c0+15 (f32)
            #pragma unroll
            for (int j = 0; j < 4; j++) {
                float4 b = *(const float4*)&br1[c0 + j * 4];
                float4 o = make_float4(silu_f(a[j*4+0]+b.x), silu_f(a[j*4+1]+b.y),
                                       silu_f(a[j*4+2]+b.z), silu_f(a[j*4+3]+b.w));
                *(float4*)&r1[(size_t)row * 64 + c0 + j * 4] = o;
            }
        }
    }
}

// h = silu(dinv[dst]*(sum_src h0s + h0s[dst]) + b1) + r1*alpha1 ; in place over r1
extern "C" __global__ __launch_bounds__(256) void k_agg1(
    const unsigned short* __restrict__ h0s, const int* __restrict__ rowstart,
    const int* __restrict__ deg, const int* __restrict__ csr,
    const float* __restrict__ dinv, const float* __restrict__ b1,
    const float* __restrict__ alpha1, float* __restrict__ r1h, int n)
{
    int wave = threadIdx.x >> 6, lane = threadIdx.x & 63;
    int node = blockIdx.x * 4 + wave;
    if (node >= n) return;
    int rs = rowstart[node];
    int cnt = deg[node];
    float acc = bf2f(h0s[(size_t)node * 64 + lane]);   // self loop
    int i = 0;
    for (; i + 8 <= cnt; i += 8) {
        int s0 = csr[rs+i+0], s1 = csr[rs+i+1], s2 = csr[rs+i+2], s3 = csr[rs+i+3];
        int s4 = csr[rs+i+4], s5 = csr[rs+i+5], s6 = csr[rs+i+6], s7 = csr[rs+i+7];
        float a0 = bf2f(h0s[(size_t)s0*64+lane]), a1 = bf2f(h0s[(size_t)s1*64+lane]);
        float a2 = bf2f(h0s[(size_t)s2*64+lane]), a3 = bf2f(h0s[(size_t)s3*64+lane]);
        float a4 = bf2f(h0s[(size_t)s4*64+lane]), a5 = bf2f(h0s[(size_t)s5*64+lane]);
        float a6 = bf2f(h0s[(size_t)s6*64+lane]), a7 = bf2f(h0s[(size_t)s7*64+lane]);
        acc += ((a0+a1)+(a2+a3)) + ((a4+a5)+(a6+a7));
    }
    for (; i < cnt; i++) acc += bf2f(h0s[(size_t)csr[rs+i]*64+lane]);
    float v = dinv[node] * acc + b1[lane];
    float hv = silu_f(v) + r1h[(size_t)node * 64 + lane] * alpha1[0];
    r1h[(size_t)node * 64 + lane] = hv;
}

// h2s = (h @ W2) * dinv ; r2 = silu(h @ Wr2 + br2)
extern "C" __global__ __launch_bounds__(256) void k_gemm2(
    const float* __restrict__ h, const float* __restrict__ W2, const float* __restrict__ Wr2,
    const float* __restrict__ br2, const float* __restrict__ dinv,
    float* __restrict__ h2s, float* __restrict__ r2, int n)
{
    __shared__ float xsT[64 * 132];
    __shared__ float wsm[64 * 32];
    int t = threadIdx.x;
    int r0 = blockIdx.x * 128;
    int rg = t >> 3;
    int cg = t & 7;
    float acc[4][4] = {};

    #pragma unroll
    for (int i = 0; i < 8; i++) {
        int u = t + i * 256;
        int row = u >> 4, kq = u & 15;
        float4 v = make_float4(0.f, 0.f, 0.f, 0.f);
        int grow = r0 + row;
        if (grow < n) v = *(const float4*)&h[(size_t)grow * 64 + kq * 4];
        xsT[(kq * 4 + 0) * 132 + row] = v.x;
        xsT[(kq * 4 + 1) * 132 + row] = v.y;
        xsT[(kq * 4 + 2) * 132 + row] = v.z;
        xsT[(kq * 4 + 3) * 132 + row] = v.w;
    }
    #pragma unroll
    for (int i = 0; i < 2; i++) {
        int ul = t + i * 256;
        int k = ul >> 3, u = ul & 7;
        int c = u * 4;
        float4 v;
        if (c < 16) v = *(const float4*)&W2[(size_t)k * 16 + c];
        else        v = *(const float4*)&Wr2[(size_t)k * 16 + (c - 16)];
        *(float4*)&wsm[k * 32 + c] = v;
    }
    __syncthreads();

    const float* xbase = &xsT[rg * 4];
    const float* wbase = &wsm[cg * 4];
    #pragma unroll
    for (int k = 0; k < 64; k++) {
        float4 xa = *(const float4*)&xbase[k * 132];
        float4 wa = *(const float4*)&wbase[k * 32];
        float xv[4] = {xa.x, xa.y, xa.z, xa.w};
        float wv[4] = {wa.x, wa.y, wa.z, wa.w};
        #pragma unroll
        for (int i = 0; i < 4; i++)
            #pragma unroll
            for (int j = 0; j < 4; j++) acc[i][j] += xv[i] * wv[j];
    }

    if (cg < 4) {
        int c0 = cg * 4;
        #pragma unroll
        for (int i = 0; i < 4; i++) {
            int row = r0 + rg * 4 + i;
            if (row >= n) break;
            float dv = dinv[row];
            float4 o = make_float4(acc[i][0]*dv, acc[i][1]*dv, acc[i][2]*dv, acc[i][3]*dv);
            *(float4*)&h2s[(size_t)row * 16 + c0] = o;
        }
    } else {
        int c0 = (cg - 4) * 4;
        float4 b = *(const float4*)&br2[c0];
        #pragma unroll
        for (int i = 0; i < 4; i++) {
            int row = r0 + rg * 4 + i;
            if (row >= n) break;
            float4 o = make_float4(silu_f(acc[i][0]+b.x), silu_f(acc[i][1]+b.y),
                                   silu_f(acc[i][2]+b.z), silu_f(acc[i][3]+b.w));
            *(float4*)&r2[(size_t)row * 16 + c0] = o;
        }
    }
}

// z = dinv[dst]*(sum h2s + h2s[dst]) + b2 + r2*alpha2 ; in place over r2
extern "C" __global__ __launch_bounds__(256) void k_agg2(
    const float* __restrict__ h2s, const int* __restrict__ rowstart, const int* __restrict__ deg,
    const int* __restrict__ csr, const float* __restrict__ dinv, const float* __restrict__ b2,
    const float* __restrict__ alpha2, float* __restrict__ r2z, int n)
{
    int wave = threadIdx.x >> 6, lane = threadIdx.x & 63;
    int node = blockIdx.x * 4 + wave;
    if (node >= n) return;
    int rs = rowstart[node], cnt = deg[node];
    int sub = lane >> 4, j = lane & 15;
    float acc = 0.0f;
    int i = sub;
    for (; i + 8 <= cnt; i += 8) {
        int sa = csr[rs + i], sb = csr[rs + i + 4];
        acc += h2s[(size_t)sa * 16 + j] + h2s[(size_t)sb * 16 + j];
    }
    for (; i < cnt; i += 4) acc += h2s[(size_t)csr[rs + i] * 16 + j];
    acc += __shfl_xor(acc, 16, 64);
    acc += __shfl_xor(acc, 32, 64);
    if (sub == 0) {
        acc += h2s[(size_t)node * 16 + j];
        float v = dinv[node] * acc + b2[j] + r2z[(size_t)node * 16 + j] * alpha2[0];
        r2z[(size_t)node * 16 + j] = v;
    }
}

// fused pool + metrics MLP + classifier head; one block per graph
extern "C" __global__ __launch_bounds__(256) void k_poolhead(
    const float* __restrict__ z, const int* __restrict__ batch,
    const float* __restrict__ tol, const float* __restrict__ cost,
    const float* __restrict__ time_, const float* __restrict__ qty,
    const float* __restrict__ mW1, const float* __restrict__ mb1,
    const float* __restrict__ mW2, const float* __restrict__ mb2,
    const float* __restrict__ Wf1, const float* __restrict__ bf1,
    const float* __restrict__ Wf2, const float* __restrict__ bf2,
    float* __restrict__ out, int n, int NC)
{
    int g = blockIdx.x;
    __shared__ float comb[80];
    __shared__ float part[16][17];
    __shared__ float hidden[80];
    int t = threadIdx.x;

    int lo = 0, hi = n;
    while (lo < hi) { int m = (lo + hi) >> 1; if (batch[m] < g) lo = m + 1; else hi = m; }
    int start = lo;
    lo = start; hi = n;
    while (lo < hi) { int m = (lo + hi) >> 1; if (batch[m] < g + 1) lo = m + 1; else hi = m; }
    int end = lo;

    int j = t & 15, grp = t >> 4;
    float acc = 0.0f;
    for (int r = start + grp; r < end; r += 16) acc += z[(size_t)r * 16 + j];
    part[grp][j] = acc;
    __syncthreads();
    if (t < 16) {
        float s = 0.0f;
        #pragma unroll
        for (int q = 0; q < 16; q++) s += part[q][t];
        comb[t] = s / fmaxf((float)(end - start), 1.0f);
    } else if (t >= 64 && t < 128) {
        int tt = t - 64;
        int i = tt >> 4, jj = tt & 15;
        float mv = (i == 0) ? tol[0] : (i == 1) ? cost[0] : (i == 2) ? time_[0] : qty[0];
        float a = mb2[i * 16 + jj];
        #pragma unroll
        for (int k = 0; k < 8; k++) {
            float hpre = mv * mW1[i * 8 + k] + mb1[i * 8 + k];
            a += silu_f(hpre) * mW2[i * 128 + k * 16 + jj];
        }
        comb[16 + tt] = a;
    }
    __syncthreads();
    if (t < 80) {
        float a = bf1[t];
        #pragma unroll 8
        for (int k = 0; k < 80; k++) a += comb[k] * Wf1[k * 80 + t];
        hidden[t] = silu_f(a);
    }
    __syncthreads();
    if (t < NC) {
        float a = bf2[t];
        #pragma unroll 8
        for (int k = 0; k < 80; k++) a += hidden[k] * Wf2[k * NC + t];
        out[g * NC + t] = a;
    }
}

extern "C" void kernel_launch(void* const* d_in, const int* in_sizes, int n_in,
                              void* d_out, int out_size, void* d_ws, size_t ws_size,
                              hipStream_t stream)
{
    const float* x     = (const float*)d_in[0];
    const int*   ei    = (const int*)d_in[1];
    const int*   batch = (const int*)d_in[2];
    const float* tol   = (const float*)d_in[3];
    const float* cost  = (const float*)d_in[4];
    const float* time_ = (const float*)d_in[5];
    const float* qty   = (const float*)d_in[6];
    const float* W1    = (const float*)d_in[7];
    const float* b1    = (const float*)d_in[8];
    const float* W2    = (const float*)d_in[9];
    const float* b2    = (const float*)d_in[10];
    const float* Wr1   = (const float*)d_in[11];
    const float* br1   = (const float*)d_in[12];
    const float* Wr2   = (const float*)d_in[13];
    const float* br2   = (const float*)d_in[14];
    const float* alpha1= (const float*)d_in[15];
    const float* alpha2= (const float*)d_in[16];
    const float* mW1   = (const float*)d_in[17];
    const float* mb1   = (const float*)d_in[18];
    const float* mW2   = (const float*)d_in[19];
    const float* mb2   = (const float*)d_in[20];
    const float* Wf1   = (const float*)d_in[21];
    const float* bf1   = (const float*)d_in[22];
    const float* Wf2   = (const float*)d_in[23];
    const float* bf2   = (const float*)d_in[24];

    const int N  = in_sizes[2];
    const int E  = in_sizes[1] / 2;
    const int NC = in_sizes[24];
    const int G  = out_size / NC;

    const int* srcIdx = ei;
    const int* dstIdx = ei + E;

    int shift = 8;
    while (((N + (1 << shift) - 1) >> shift) > 512) shift++;
    const int nbkt = (N + (1 << shift) - 1) >> shift;

    char* w = (char*)d_ws;
    auto alloc = [&](size_t bytes) { char* p = w; w += (bytes + 255) & ~(size_t)255; return p; };
    int*   deg      = (int*)alloc((size_t)N * 4);
    int*   rowstart = (int*)alloc((size_t)N * 4);
    int*   bcount   = (int*)alloc(2048);
    int*   boff     = (int*)alloc(2052 + 252);
    int*   bcursor  = (int*)alloc(2048);
    int*   csr      = (int*)alloc((size_t)E * 4);
    int2*  ebuf     = (int2*)alloc((size_t)E * 8);
    float* dinv     = (float*)alloc((size_t)N * 4);
    unsigned short* h0sb = (unsigned short*)alloc((size_t)N * 64 * 2);  // bf16 gather table
    float* bufA     = (float*)alloc((size_t)N * 64 * 4);  // h2s (gemm2 out)
    float* bufB     = (float*)alloc((size_t)N * 64 * 4);  // r1, later h (in place)
    float* bufC     = (float*)alloc((size_t)N * 16 * 4);  // r2, later z (in place)

    hipMemsetAsync(bcount, 0, 2048, stream);

    int EB8 = (E + 8191) / 8192;

    k_bhist   <<<EB8, 256, 0, stream>>>(dstIdx, bcount, E, nbkt, shift);
    k_bscan   <<<1, 512, 0, stream>>>(bcount, boff, bcursor, nbkt);
    k_bscatter<<<EB8, 256, 0, stream>>>(srcIdx, dstIdx, bcursor, ebuf, E, nbkt, shift);
    k_bcsr    <<<nbkt, 256, 0, stream>>>(ebuf, boff, deg, dinv, rowstart, csr, shift, N);

    k_gemm1<<<(N + 127) / 128, 512, 0, stream>>>(x, W1, Wr1, br1, dinv, h0sb, bufB, N);
    k_agg1 <<<(N + 3) / 4, 256, 0, stream>>>(h0sb, rowstart, deg, csr, dinv, b1, alpha1, bufB, N);
    k_gemm2<<<(N + 127) / 128, 256, 0, stream>>>(bufB, W2, Wr2, br2, dinv, bufA, bufC, N);
    k_agg2 <<<(N + 3) / 4, 256, 0, stream>>>(bufA, rowstart, deg, csr, dinv, b2, alpha2, bufC, N);
    k_poolhead<<<G, 256, 0, stream>>>(bufC, batch, tol, cost, time_, qty,
                                      mW1, mb1, mW2, mb2, Wf1, bf1, Wf2, bf2,
                                      (float*)d_out, N, NC);
}

// Round 15
// 266.021 us; speedup vs baseline: 1.3033x; 1.3033x over previous
//
#include <hip/hip_runtime.h>

static __device__ __forceinline__ float silu_f(float v) {
    return v / (1.0f + __expf(-v));
}
// bf16 pack/unpack (RNE)
static __device__ __forceinline__ unsigned short f2bf(float f) {
    unsigned int u = __float_as_uint(f);
    u = (u + 0x7FFFu + ((u >> 16) & 1u)) >> 16;
    return (unsigned short)u;
}
static __device__ __forceinline__ float bf2f(unsigned short h) {
    return __uint_as_float(((unsigned int)h) << 16);
}

// ---------------- bucketed CSR build ----------------

extern "C" __global__ __launch_bounds__(256) void k_bhist(
    const int* __restrict__ dst, int* __restrict__ bcount, int E, int nbkt, int shift)
{
    __shared__ int lh[512];
    int t = threadIdx.x;
    for (int i = t; i < 512; i += 256) lh[i] = 0;
    __syncthreads();
    int e0 = blockIdx.x * 8192;
    #pragma unroll 4
    for (int i = 0; i < 32; i++) {
        int e = e0 + t + i * 256;
        if (e < E) atomicAdd(&lh[dst[e] >> shift], 1);
    }
    __syncthreads();
    for (int b = t; b < nbkt; b += 256)
        if (lh[b]) atomicAdd(&bcount[b], lh[b]);
}

extern "C" __global__ __launch_bounds__(512) void k_bscan(
    const int* __restrict__ bcount, int* __restrict__ boff, int* __restrict__ bcursor, int nbkt)
{
    __shared__ int sc[512];
    int t = threadIdx.x;
    int v = (t < nbkt) ? bcount[t] : 0;
    sc[t] = v;
    __syncthreads();
    for (int off = 1; off < 512; off <<= 1) {
        int add = (t >= off) ? sc[t - off] : 0;
        __syncthreads();
        sc[t] += add;
        __syncthreads();
    }
    int excl = sc[t] - v;
    if (t < nbkt) { boff[t] = excl; bcursor[t] = excl; }
    if (t == nbkt - 1) boff[nbkt] = excl + v;
}

extern "C" __global__ __launch_bounds__(256) void k_bscatter(
    const int* __restrict__ src, const int* __restrict__ dst, int* __restrict__ bcursor,
    int2* __restrict__ ebuf, int E, int nbkt, int shift)
{
    __shared__ int lh[512];
    __shared__ int lbase[512];
    int t = threadIdx.x;
    for (int i = t; i < 512; i += 256) lh[i] = 0;
    __syncthreads();
    int e0 = blockIdx.x * 8192;
    #pragma unroll 4
    for (int i = 0; i < 32; i++) {
        int e = e0 + t + i * 256;
        if (e < E) atomicAdd(&lh[dst[e] >> shift], 1);
    }
    __syncthreads();
    for (int b = t; b < nbkt; b += 256)
        lbase[b] = lh[b] ? atomicAdd(&bcursor[b], lh[b]) : 0;
    __syncthreads();
    #pragma unroll 4
    for (int i = 0; i < 32; i++) {
        int e = e0 + t + i * 256;
        if (e < E) {
            int d = dst[e];
            int p = atomicAdd(&lbase[d >> shift], 1);
            ebuf[p] = make_int2(src[e], d);
        }
    }
}

// fused: per-bucket deg/dinv/rowstart + CSR fill (ebuf window stays L2-hot)
extern "C" __global__ __launch_bounds__(256) void k_bcsr(
    const int2* __restrict__ ebuf, const int* __restrict__ boff,
    int* __restrict__ deg, float* __restrict__ dinv, int* __restrict__ rowstart,
    int* __restrict__ csr, int shift, int N)
{
    int b = blockIdx.x;
    int W = 1 << shift;
    __shared__ int lcur[4096];
    __shared__ int sc[256];
    int t = threadIdx.x;
    for (int i = t; i < W; i += 256) lcur[i] = 0;
    __syncthreads();
    int s = boff[b], e_ = boff[b + 1];
    for (int e = s + t; e < e_; e += 256)
        atomicAdd(&lcur[ebuf[e].y - (b << shift)], 1);
    __syncthreads();

    int c = W >> 8;
    int base = t * c;
    int mysum = 0;
    for (int i = 0; i < c; i++) mysum += lcur[base + i];
    sc[t] = mysum;
    __syncthreads();
    int mine = mysum;
    for (int off = 1; off < 256; off <<= 1) {
        int add = (t >= off) ? sc[t - off] : 0;
        __syncthreads();
        sc[t] += add;
        __syncthreads();
    }
    int run = sc[t] - mine + s;
    int nbase = b << shift;
    for (int i = 0; i < c; i++) {
        int d = lcur[base + i];
        int node = nbase + base + i;
        if (node < N) {
            rowstart[node] = run;
            deg[node] = d;
            dinv[node] = rsqrtf((float)(d + 1));
        }
        lcur[base + i] = run;       // becomes absolute fill cursor
        run += d;
    }
    __syncthreads();
    for (int e = s + t; e < e_; e += 256) {
        int2 p = ebuf[e];
        int pos = atomicAdd(&lcur[p.y - (b << shift)], 1);
        csr[pos] = p.x;
    }
}

// ---------------- gemm1: h0s(bf16) = (x@W1)*dinv ; r1 = silu(x@Wr1+br1) ----------------
// R13 structure (measured 75us): 128 rows/block, 512 threads = 8 waves;
// wave -> 16-col slice (wv<4: W1, else Wr1; uniform via readfirstlane);
// 2 rows/lane; per k: 4 uniform s_load_dwordx4 + 2 ds_read + 32 FMA.
extern "C" __global__ __launch_bounds__(512) void k_gemm1(
    const float* __restrict__ x, const float* __restrict__ W1, const float* __restrict__ Wr1,
    const float* __restrict__ br1, const float* __restrict__ dinv,
    unsigned short* __restrict__ h0s, float* __restrict__ r1, int n)
{
    __shared__ float xs[128 * 36];
    int t = threadIdx.x;
    int lane = t & 63;
    int wv = __builtin_amdgcn_readfirstlane(t >> 6);   // 0..7
    const float* Wp = (wv < 4) ? W1 : Wr1;
    const int c0 = (wv & 3) * 16;
    int r0 = blockIdx.x * 128;

    float acc0[16] = {}, acc1[16] = {};
    float4 px[2];

    #pragma unroll
    for (int i = 0; i < 2; i++) {          // chunk-0 prefetch (1024 f4 / 512 thr)
        int u = t + i * 512;
        int rr = u >> 3, kq = u & 7;
        px[i] = make_float4(0.f, 0.f, 0.f, 0.f);
        if (r0 + rr < n) px[i] = *(const float4*)&x[(size_t)(r0 + rr) * 128 + kq * 4];
    }

    for (int kk = 0; kk < 128; kk += 32) {
        if (kk) __syncthreads();
        #pragma unroll
        for (int i = 0; i < 2; i++) {
            int u = t + i * 512;
            int rr = u >> 3, kq = u & 7;
            *(float4*)&xs[rr * 36 + kq * 4] = px[i];
        }
        __syncthreads();
        if (kk < 96) {                     // prefetch next chunk under FMA loop
            int kn = kk + 32;
            #pragma unroll
            for (int i = 0; i < 2; i++) {
                int u = t + i * 512;
                int rr = u >> 3, kq = u & 7;
                px[i] = make_float4(0.f, 0.f, 0.f, 0.f);
                if (r0 + rr < n) px[i] = *(const float4*)&x[(size_t)(r0 + rr) * 128 + kn + kq * 4];
            }
        }
        #pragma unroll
        for (int kb = 0; kb < 8; kb++) {   // 4 k's per kb
            float4 xa = *(const float4*)&xs[lane * 36 + kb * 4];
            float4 xb = *(const float4*)&xs[(lane + 64) * 36 + kb * 4];
            float xv0[4] = {xa.x, xa.y, xa.z, xa.w};
            float xv1[4] = {xb.x, xb.y, xb.z, xb.w};
            #pragma unroll
            for (int kq = 0; kq < 4; kq++) {
                const float* wrow = &Wp[(size_t)(kk + kb * 4 + kq) * 64 + c0];
                #pragma unroll
                for (int j = 0; j < 4; j++) {
                    float4 w4 = *(const float4*)&wrow[j * 4];
                    acc0[j*4+0] += xv0[kq] * w4.x; acc1[j*4+0] += xv1[kq] * w4.x;
                    acc0[j*4+1] += xv0[kq] * w4.y; acc1[j*4+1] += xv1[kq] * w4.y;
                    acc0[j*4+2] += xv0[kq] * w4.z; acc1[j*4+2] += xv1[kq] * w4.z;
                    acc0[j*4+3] += xv0[kq] * w4.w; acc1[j*4+3] += xv1[kq] * w4.w;
                }
            }
        }
    }

    #pragma unroll
    for (int half = 0; half < 2; half++) {
        int row = r0 + half * 64 + lane;
        if (row >= n) continue;
        const float* a = half ? acc1 : acc0;
        if (wv < 4) {                      // h0s (bf16) cols c0..c0+15
            float dv = dinv[row];
            uint4 o0, o1;
            unsigned int* po = &o0.x;
            #pragma unroll
            for (int q = 0; q < 8; q++) {
                unsigned int lo = f2bf(a[q*2+0] * dv);
                unsigned int hi = f2bf(a[q*2+1] * dv);
                po[q] = lo | (hi << 16);
            }
            uint4* dst0 = (uint4*)&h0s[(size_t)row * 64 + c0];
            dst0[0] = o0; dst0[1] = o1;
        } else {                           // r1 cols c0..c0+15 (f32)
            #pragma unroll
            for (int j = 0; j < 4; j++) {
                float4 b = *(const float4*)&br1[c0 + j * 4];
                float4 o = make_float4(silu_f(a[j*4+0]+b.x), silu_f(a[j*4+1]+b.y),
                                       silu_f(a[j*4+2]+b.z), silu_f(a[j*4+3]+b.w));
                *(float4*)&r1[(size_t)row * 64 + c0 + j * 4] = o;
            }
        }
    }
}

// h = silu(dinv[dst]*(sum_src h0s + h0s[dst]) + b1) + r1*alpha1 ; in place over r1
extern "C" __global__ __launch_bounds__(256) void k_agg1(
    const unsigned short* __restrict__ h0s, const int* __restrict__ rowstart,
    const int* __restrict__ deg, const int* __restrict__ csr,
    const float* __restrict__ dinv, const float* __restrict__ b1,
    const float* __restrict__ alpha1, float* __restrict__ r1h, int n)
{
    int wave = threadIdx.x >> 6, lane = threadIdx.x & 63;
    int node = blockIdx.x * 4 + wave;
    if (node >= n) return;
    int rs = rowstart[node];
    int cnt = deg[node];
    float acc = bf2f(h0s[(size_t)node * 64 + lane]);   // self loop
    int i = 0;
    for (; i + 8 <= cnt; i += 8) {
        int s0 = csr[rs+i+0], s1 = csr[rs+i+1], s2 = csr[rs+i+2], s3 = csr[rs+i+3];
        int s4 = csr[rs+i+4], s5 = csr[rs+i+5], s6 = csr[rs+i+6], s7 = csr[rs+i+7];
        float a0 = bf2f(h0s[(size_t)s0*64+lane]), a1 = bf2f(h0s[(size_t)s1*64+lane]);
        float a2 = bf2f(h0s[(size_t)s2*64+lane]), a3 = bf2f(h0s[(size_t)s3*64+lane]);
        float a4 = bf2f(h0s[(size_t)s4*64+lane]), a5 = bf2f(h0s[(size_t)s5*64+lane]);
        float a6 = bf2f(h0s[(size_t)s6*64+lane]), a7 = bf2f(h0s[(size_t)s7*64+lane]);
        acc += ((a0+a1)+(a2+a3)) + ((a4+a5)+(a6+a7));
    }
    for (; i < cnt; i++) acc += bf2f(h0s[(size_t)csr[rs+i]*64+lane]);
    float v = dinv[node] * acc + b1[lane];
    float hv = silu_f(v) + r1h[(size_t)node * 64 + lane] * alpha1[0];
    r1h[(size_t)node * 64 + lane] = hv;
}

// h2s(bf16) = (h @ W2) * dinv ; r2 = silu(h @ Wr2 + br2)
extern "C" __global__ __launch_bounds__(256) void k_gemm2(
    const float* __restrict__ h, const float* __restrict__ W2, const float* __restrict__ Wr2,
    const float* __restrict__ br2, const float* __restrict__ dinv,
    unsigned short* __restrict__ h2s, float* __restrict__ r2, int n)
{
    __shared__ float xsT[64 * 132];
    __shared__ float wsm[64 * 32];
    int t = threadIdx.x;
    int r0 = blockIdx.x * 128;
    int rg = t >> 3;
    int cg = t & 7;
    float acc[4][4] = {};

    #pragma unroll
    for (int i = 0; i < 8; i++) {
        int u = t + i * 256;
        int row = u >> 4, kq = u & 15;
        float4 v = make_float4(0.f, 0.f, 0.f, 0.f);
        int grow = r0 + row;
        if (grow < n) v = *(const float4*)&h[(size_t)grow * 64 + kq * 4];
        xsT[(kq * 4 + 0) * 132 + row] = v.x;
        xsT[(kq * 4 + 1) * 132 + row] = v.y;
        xsT[(kq * 4 + 2) * 132 + row] = v.z;
        xsT[(kq * 4 + 3) * 132 + row] = v.w;
    }
    #pragma unroll
    for (int i = 0; i < 2; i++) {
        int ul = t + i * 256;
        int k = ul >> 3, u = ul & 7;
        int c = u * 4;
        float4 v;
        if (c < 16) v = *(const float4*)&W2[(size_t)k * 16 + c];
        else        v = *(const float4*)&Wr2[(size_t)k * 16 + (c - 16)];
        *(float4*)&wsm[k * 32 + c] = v;
    }
    __syncthreads();

    const float* xbase = &xsT[rg * 4];
    const float* wbase = &wsm[cg * 4];
    #pragma unroll
    for (int k = 0; k < 64; k++) {
        float4 xa = *(const float4*)&xbase[k * 132];
        float4 wa = *(const float4*)&wbase[k * 32];
        float xv[4] = {xa.x, xa.y, xa.z, xa.w};
        float wv[4] = {wa.x, wa.y, wa.z, wa.w};
        #pragma unroll
        for (int i = 0; i < 4; i++)
            #pragma unroll
            for (int j = 0; j < 4; j++) acc[i][j] += xv[i] * wv[j];
    }

    if (cg < 4) {                         // h2s (bf16) cols cg*4..+3
        int c0 = cg * 4;
        #pragma unroll
        for (int i = 0; i < 4; i++) {
            int row = r0 + rg * 4 + i;
            if (row >= n) break;
            float dv = dinv[row];
            unsigned int w0 = f2bf(acc[i][0]*dv) | ((unsigned int)f2bf(acc[i][1]*dv) << 16);
            unsigned int w1 = f2bf(acc[i][2]*dv) | ((unsigned int)f2bf(acc[i][3]*dv) << 16);
            uint2 o = make_uint2(w0, w1);
            *(uint2*)&h2s[(size_t)row * 16 + c0] = o;
        }
    } else {                              // r2 cols 0..15 (f32)
        int c0 = (cg - 4) * 4;
        float4 b = *(const float4*)&br2[c0];
        #pragma unroll
        for (int i = 0; i < 4; i++) {
            int row = r0 + rg * 4 + i;
            if (row >= n) break;
            float4 o = make_float4(silu_f(acc[i][0]+b.x), silu_f(acc[i][1]+b.y),
                                   silu_f(acc[i][2]+b.z), silu_f(acc[i][3]+b.w));
            *(float4*)&r2[(size_t)row * 16 + c0] = o;
        }
    }
}

// z = dinv[dst]*(sum h2s + h2s[dst]) + b2 + r2*alpha2 ; in place over r2
// h2s is bf16: 3.2 MB table -> fits per-XCD L2 (4 MB) -> near-one-fetch gather.
extern "C" __global__ __launch_bounds__(256) void k_agg2(
    const unsigned short* __restrict__ h2s, const int* __restrict__ rowstart,
    const int* __restrict__ deg, const int* __restrict__ csr,
    const float* __restrict__ dinv, const float* __restrict__ b2,
    const float* __restrict__ alpha2, float* __restrict__ r2z, int n)
{
    int wave = threadIdx.x >> 6, lane = threadIdx.x & 63;
    int node = blockIdx.x * 4 + wave;
    if (node >= n) return;
    int rs = rowstart[node], cnt = deg[node];
    int sub = lane >> 4, j = lane & 15;
    float acc = 0.0f;
    int i = sub;
    for (; i + 8 <= cnt; i += 8) {
        int sa = csr[rs + i], sb = csr[rs + i + 4];
        acc += bf2f(h2s[(size_t)sa * 16 + j]) + bf2f(h2s[(size_t)sb * 16 + j]);
    }
    for (; i < cnt; i += 4) acc += bf2f(h2s[(size_t)csr[rs + i] * 16 + j]);
    acc += __shfl_xor(acc, 16, 64);
    acc += __shfl_xor(acc, 32, 64);
    if (sub == 0) {
        acc += bf2f(h2s[(size_t)node * 16 + j]);
        float v = dinv[node] * acc + b2[j] + r2z[(size_t)node * 16 + j] * alpha2[0];
        r2z[(size_t)node * 16 + j] = v;
    }
}

// fused pool + metrics MLP + classifier head; one block per graph
extern "C" __global__ __launch_bounds__(256) void k_poolhead(
    const float* __restrict__ z, const int* __restrict__ batch,
    const float* __restrict__ tol, const float* __restrict__ cost,
    const float* __restrict__ time_, const float* __restrict__ qty,
    const float* __restrict__ mW1, const float* __restrict__ mb1,
    const float* __restrict__ mW2, const float* __restrict__ mb2,
    const float* __restrict__ Wf1, const float* __restrict__ bf1,
    const float* __restrict__ Wf2, const float* __restrict__ bf2,
    float* __restrict__ out, int n, int NC)
{
    int g = blockIdx.x;
    __shared__ float comb[80];
    __shared__ float part[16][17];
    __shared__ float hidden[80];
    int t = threadIdx.x;

    int lo = 0, hi = n;
    while (lo < hi) { int m = (lo + hi) >> 1; if (batch[m] < g) lo = m + 1; else hi = m; }
    int start = lo;
    lo = start; hi = n;
    while (lo < hi) { int m = (lo + hi) >> 1; if (batch[m] < g + 1) lo = m + 1; else hi = m; }
    int end = lo;

    int j = t & 15, grp = t >> 4;
    float acc = 0.0f;
    for (int r = start + grp; r < end; r += 16) acc += z[(size_t)r * 16 + j];
    part[grp][j] = acc;
    __syncthreads();
    if (t < 16) {
        float s = 0.0f;
        #pragma unroll
        for (int q = 0; q < 16; q++) s += part[q][t];
        comb[t] = s / fmaxf((float)(end - start), 1.0f);
    } else if (t >= 64 && t < 128) {
        int tt = t - 64;
        int i = tt >> 4, jj = tt & 15;
        float mv = (i == 0) ? tol[0] : (i == 1) ? cost[0] : (i == 2) ? time_[0] : qty[0];
        float a = mb2[i * 16 + jj];
        #pragma unroll
        for (int k = 0; k < 8; k++) {
            float hpre = mv * mW1[i * 8 + k] + mb1[i * 8 + k];
            a += silu_f(hpre) * mW2[i * 128 + k * 16 + jj];
        }
        comb[16 + tt] = a;
    }
    __syncthreads();
    if (t < 80) {
        float a = bf1[t];
        #pragma unroll 8
        for (int k = 0; k < 80; k++) a += comb[k] * Wf1[k * 80 + t];
        hidden[t] = silu_f(a);
    }
    __syncthreads();
    if (t < NC) {
        float a = bf2[t];
        #pragma unroll 8
        for (int k = 0; k < 80; k++) a += hidden[k] * Wf2[k * NC + t];
        out[g * NC + t] = a;
    }
}

extern "C" void kernel_launch(void* const* d_in, const int* in_sizes, int n_in,
                              void* d_out, int out_size, void* d_ws, size_t ws_size,
                              hipStream_t stream)
{
    const float* x     = (const float*)d_in[0];
    const int*   ei    = (const int*)d_in[1];
    const int*   batch = (const int*)d_in[2];
    const float* tol   = (const float*)d_in[3];
    const float* cost  = (const float*)d_in[4];
    const float* time_ = (const float*)d_in[5];
    const float* qty   = (const float*)d_in[6];
    const float* W1    = (const float*)d_in[7];
    const float* b1    = (const float*)d_in[8];
    const float* W2    = (const float*)d_in[9];
    const float* b2    = (const float*)d_in[10];
    const float* Wr1   = (const float*)d_in[11];
    const float* br1   = (const float*)d_in[12];
    const float* Wr2   = (const float*)d_in[13];
    const float* br2   = (const float*)d_in[14];
    const float* alpha1= (const float*)d_in[15];
    const float* alpha2= (const float*)d_in[16];
    const float* mW1   = (const float*)d_in[17];
    const float* mb1   = (const float*)d_in[18];
    const float* mW2   = (const float*)d_in[19];
    const float* mb2   = (const float*)d_in[20];
    const float* Wf1   = (const float*)d_in[21];
    const float* bf1   = (const float*)d_in[22];
    const float* Wf2   = (const float*)d_in[23];
    const float* bf2   = (const float*)d_in[24];

    const int N  = in_sizes[2];
    const int E  = in_sizes[1] / 2;
    const int NC = in_sizes[24];
    const int G  = out_size / NC;

    const int* srcIdx = ei;
    const int* dstIdx = ei + E;

    int shift = 8;
    while (((N + (1 << shift) - 1) >> shift) > 512) shift++;
    const int nbkt = (N + (1 << shift) - 1) >> shift;

    char* w = (char*)d_ws;
    auto alloc = [&](size_t bytes) { char* p = w; w += (bytes + 255) & ~(size_t)255; return p; };
    int*   deg      = (int*)alloc((size_t)N * 4);
    int*   rowstart = (int*)alloc((size_t)N * 4);
    int*   bcount   = (int*)alloc(2048);
    int*   boff     = (int*)alloc(2052 + 252);
    int*   bcursor  = (int*)alloc(2048);
    int*   csr      = (int*)alloc((size_t)E * 4);
    int2*  ebuf     = (int2*)alloc((size_t)E * 8);
    float* dinv     = (float*)alloc((size_t)N * 4);
    unsigned short* h0sb = (unsigned short*)alloc((size_t)N * 64 * 2);  // bf16 gather table
    unsigned short* h2sb = (unsigned short*)alloc((size_t)N * 16 * 2);  // bf16 gather table (agg2)
    float* bufB     = (float*)alloc((size_t)N * 64 * 4);  // r1, later h (in place)
    float* bufC     = (float*)alloc((size_t)N * 16 * 4);  // r2, later z (in place)

    hipMemsetAsync(bcount, 0, 2048, stream);

    int EB8 = (E + 8191) / 8192;

    k_bhist   <<<EB8, 256, 0, stream>>>(dstIdx, bcount, E, nbkt, shift);
    k_bscan   <<<1, 512, 0, stream>>>(bcount, boff, bcursor, nbkt);
    k_bscatter<<<EB8, 256, 0, stream>>>(srcIdx, dstIdx, bcursor, ebuf, E, nbkt, shift);
    k_bcsr    <<<nbkt, 256, 0, stream>>>(ebuf, boff, deg, dinv, rowstart, csr, shift, N);

    k_gemm1<<<(N + 127) / 128, 512, 0, stream>>>(x, W1, Wr1, br1, dinv, h0sb, bufB, N);
    k_agg1 <<<(N + 3) / 4, 256, 0, stream>>>(h0sb, rowstart, deg, csr, dinv, b1, alpha1, bufB, N);
    k_gemm2<<<(N + 127) / 128, 256, 0, stream>>>(bufB, W2, Wr2, br2, dinv, h2sb, bufC, N);
    k_agg2 <<<(N + 3) / 4, 256, 0, stream>>>(h2sb, rowstart, deg, csr, dinv, b2, alpha2, bufC, N);
    k_poolhead<<<G, 256, 0, stream>>>(bufC, batch, tol, cost, time_, qty,
                                      mW1, mb1, mW2, mb2, Wf1, bf1, Wf2, bf2,
                                      (float*)d_out, N, NC);
}

// Round 16
// 245.046 us; speedup vs baseline: 1.4148x; 1.0856x over previous
//
#include <hip/hip_runtime.h>

static __device__ __forceinline__ float silu_f(float v) {
    return v / (1.0f + __expf(-v));
}
// bf16 pack/unpack (RNE)
static __device__ __forceinline__ unsigned short f2bf(float f) {
    unsigned int u = __float_as_uint(f);
    u = (u + 0x7FFFu + ((u >> 16) & 1u)) >> 16;
    return (unsigned short)u;
}
static __device__ __forceinline__ float bf2f(unsigned short h) {
    return __uint_as_float(((unsigned int)h) << 16);
}
static __device__ __forceinline__ float bfLo(unsigned int v) {
    return __uint_as_float(v << 16);
}
static __device__ __forceinline__ float bfHi(unsigned int v) {
    return __uint_as_float(v & 0xFFFF0000u);
}

// ---------------- bucketed CSR build ----------------

extern "C" __global__ __launch_bounds__(256) void k_bhist(
    const int* __restrict__ dst, int* __restrict__ bcount, int E, int nbkt, int shift)
{
    __shared__ int lh[512];
    int t = threadIdx.x;
    for (int i = t; i < 512; i += 256) lh[i] = 0;
    __syncthreads();
    int e0 = blockIdx.x * 8192;
    #pragma unroll 4
    for (int i = 0; i < 32; i++) {
        int e = e0 + t + i * 256;
        if (e < E) atomicAdd(&lh[dst[e] >> shift], 1);
    }
    __syncthreads();
    for (int b = t; b < nbkt; b += 256)
        if (lh[b]) atomicAdd(&bcount[b], lh[b]);
}

extern "C" __global__ __launch_bounds__(512) void k_bscan(
    const int* __restrict__ bcount, int* __restrict__ boff, int* __restrict__ bcursor, int nbkt)
{
    __shared__ int sc[512];
    int t = threadIdx.x;
    int v = (t < nbkt) ? bcount[t] : 0;
    sc[t] = v;
    __syncthreads();
    for (int off = 1; off < 512; off <<= 1) {
        int add = (t >= off) ? sc[t - off] : 0;
        __syncthreads();
        sc[t] += add;
        __syncthreads();
    }
    int excl = sc[t] - v;
    if (t < nbkt) { boff[t] = excl; bcursor[t] = excl; }
    if (t == nbkt - 1) boff[nbkt] = excl + v;
}

extern "C" __global__ __launch_bounds__(256) void k_bscatter(
    const int* __restrict__ src, const int* __restrict__ dst, int* __restrict__ bcursor,
    int2* __restrict__ ebuf, int E, int nbkt, int shift)
{
    __shared__ int lh[512];
    __shared__ int lbase[512];
    int t = threadIdx.x;
    for (int i = t; i < 512; i += 256) lh[i] = 0;
    __syncthreads();
    int e0 = blockIdx.x * 8192;
    #pragma unroll 4
    for (int i = 0; i < 32; i++) {
        int e = e0 + t + i * 256;
        if (e < E) atomicAdd(&lh[dst[e] >> shift], 1);
    }
    __syncthreads();
    for (int b = t; b < nbkt; b += 256)
        lbase[b] = lh[b] ? atomicAdd(&bcursor[b], lh[b]) : 0;
    __syncthreads();
    #pragma unroll 4
    for (int i = 0; i < 32; i++) {
        int e = e0 + t + i * 256;
        if (e < E) {
            int d = dst[e];
            int p = atomicAdd(&lbase[d >> shift], 1);
            ebuf[p] = make_int2(src[e], d);
        }
    }
}

// fused: per-bucket deg/dinv/rowstart + CSR fill (ebuf window stays L2-hot)
extern "C" __global__ __launch_bounds__(256) void k_bcsr(
    const int2* __restrict__ ebuf, const int* __restrict__ boff,
    int* __restrict__ deg, float* __restrict__ dinv, int* __restrict__ rowstart,
    int* __restrict__ csr, int shift, int N)
{
    int b = blockIdx.x;
    int W = 1 << shift;
    __shared__ int lcur[4096];
    __shared__ int sc[256];
    int t = threadIdx.x;
    for (int i = t; i < W; i += 256) lcur[i] = 0;
    __syncthreads();
    int s = boff[b], e_ = boff[b + 1];
    for (int e = s + t; e < e_; e += 256)
        atomicAdd(&lcur[ebuf[e].y - (b << shift)], 1);
    __syncthreads();

    int c = W >> 8;
    int base = t * c;
    int mysum = 0;
    for (int i = 0; i < c; i++) mysum += lcur[base + i];
    sc[t] = mysum;
    __syncthreads();
    int mine = mysum;
    for (int off = 1; off < 256; off <<= 1) {
        int add = (t >= off) ? sc[t - off] : 0;
        __syncthreads();
        sc[t] += add;
        __syncthreads();
    }
    int run = sc[t] - mine + s;
    int nbase = b << shift;
    for (int i = 0; i < c; i++) {
        int d = lcur[base + i];
        int node = nbase + base + i;
        if (node < N) {
            rowstart[node] = run;
            deg[node] = d;
            dinv[node] = rsqrtf((float)(d + 1));
        }
        lcur[base + i] = run;       // becomes absolute fill cursor
        run += d;
    }
    __syncthreads();
    for (int e = s + t; e < e_; e += 256) {
        int2 p = ebuf[e];
        int pos = atomicAdd(&lcur[p.y - (b << shift)], 1);
        csr[pos] = p.x;
    }
}

// ---------------- gemm1: h0s(bf16) = (x@W1)*dinv ; r1 = silu(x@Wr1+br1) ----------------
// R13 structure (measured 75us): 128 rows/block, 512 threads = 8 waves;
// wave -> 16-col slice (wv<4: W1, else Wr1; uniform via readfirstlane);
// 2 rows/lane; per k: 4 uniform s_load_dwordx4 + 2 ds_read + 32 FMA.
extern "C" __global__ __launch_bounds__(512) void k_gemm1(
    const float* __restrict__ x, const float* __restrict__ W1, const float* __restrict__ Wr1,
    const float* __restrict__ br1, const float* __restrict__ dinv,
    unsigned short* __restrict__ h0s, float* __restrict__ r1, int n)
{
    __shared__ float xs[128 * 36];
    int t = threadIdx.x;
    int lane = t & 63;
    int wv = __builtin_amdgcn_readfirstlane(t >> 6);   // 0..7
    const float* Wp = (wv < 4) ? W1 : Wr1;
    const int c0 = (wv & 3) * 16;
    int r0 = blockIdx.x * 128;

    float acc0[16] = {}, acc1[16] = {};
    float4 px[2];

    #pragma unroll
    for (int i = 0; i < 2; i++) {          // chunk-0 prefetch (1024 f4 / 512 thr)
        int u = t + i * 512;
        int rr = u >> 3, kq = u & 7;
        px[i] = make_float4(0.f, 0.f, 0.f, 0.f);
        if (r0 + rr < n) px[i] = *(const float4*)&x[(size_t)(r0 + rr) * 128 + kq * 4];
    }

    for (int kk = 0; kk < 128; kk += 32) {
        if (kk) __syncthreads();
        #pragma unroll
        for (int i = 0; i < 2; i++) {
            int u = t + i * 512;
            int rr = u >> 3, kq = u & 7;
            *(float4*)&xs[rr * 36 + kq * 4] = px[i];
        }
        __syncthreads();
        if (kk < 96) {                     // prefetch next chunk under FMA loop
            int kn = kk + 32;
            #pragma unroll
            for (int i = 0; i < 2; i++) {
                int u = t + i * 512;
                int rr = u >> 3, kq = u & 7;
                px[i] = make_float4(0.f, 0.f, 0.f, 0.f);
                if (r0 + rr < n) px[i] = *(const float4*)&x[(size_t)(r0 + rr) * 128 + kn + kq * 4];
            }
        }
        #pragma unroll
        for (int kb = 0; kb < 8; kb++) {   // 4 k's per kb
            float4 xa = *(const float4*)&xs[lane * 36 + kb * 4];
            float4 xb = *(const float4*)&xs[(lane + 64) * 36 + kb * 4];
            float xv0[4] = {xa.x, xa.y, xa.z, xa.w};
            float xv1[4] = {xb.x, xb.y, xb.z, xb.w};
            #pragma unroll
            for (int kq = 0; kq < 4; kq++) {
                const float* wrow = &Wp[(size_t)(kk + kb * 4 + kq) * 64 + c0];
                #pragma unroll
                for (int j = 0; j < 4; j++) {
                    float4 w4 = *(const float4*)&wrow[j * 4];
                    acc0[j*4+0] += xv0[kq] * w4.x; acc1[j*4+0] += xv1[kq] * w4.x;
                    acc0[j*4+1] += xv0[kq] * w4.y; acc1[j*4+1] += xv1[kq] * w4.y;
                    acc0[j*4+2] += xv0[kq] * w4.z; acc1[j*4+2] += xv1[kq] * w4.z;
                    acc0[j*4+3] += xv0[kq] * w4.w; acc1[j*4+3] += xv1[kq] * w4.w;
                }
            }
        }
    }

    #pragma unroll
    for (int half = 0; half < 2; half++) {
        int row = r0 + half * 64 + lane;
        if (row >= n) continue;
        const float* a = half ? acc1 : acc0;
        if (wv < 4) {                      // h0s (bf16) cols c0..c0+15
            float dv = dinv[row];
            uint4 o0, o1;
            unsigned int* po = &o0.x;
            #pragma unroll
            for (int q = 0; q < 8; q++) {
                unsigned int lo = f2bf(a[q*2+0] * dv);
                unsigned int hi = f2bf(a[q*2+1] * dv);
                po[q] = lo | (hi << 16);
            }
            uint4* dst0 = (uint4*)&h0s[(size_t)row * 64 + c0];
            dst0[0] = o0; dst0[1] = o1;
        } else {                           // r1 cols c0..c0+15 (f32)
            #pragma unroll
            for (int j = 0; j < 4; j++) {
                float4 b = *(const float4*)&br1[c0 + j * 4];
                float4 o = make_float4(silu_f(a[j*4+0]+b.x), silu_f(a[j*4+1]+b.y),
                                       silu_f(a[j*4+2]+b.z), silu_f(a[j*4+3]+b.w));
                *(float4*)&r1[(size_t)row * 64 + c0 + j * 4] = o;
            }
        }
    }
}

// h = silu(dinv[dst]*(sum_src h0s + h0s[dst]) + b1) + r1*alpha1 ; in place over r1.
// Lane = (half, feature-pair): u32 loads (2 bf16), 2 edges per VMEM instr,
// 8 edges in flight per unrolled iter; final shfl_xor(32) merges halves.
extern "C" __global__ __launch_bounds__(256) void k_agg1(
    const unsigned short* __restrict__ h0s, const int* __restrict__ rowstart,
    const int* __restrict__ deg, const int* __restrict__ csr,
    const float* __restrict__ dinv, const float* __restrict__ b1,
    const float* __restrict__ alpha1, float* __restrict__ r1h, int n)
{
    int wave = threadIdx.x >> 6, lane = threadIdx.x & 63;
    int node = blockIdx.x * 4 + wave;
    if (node >= n) return;
    int half = lane >> 5, fl = lane & 31;         // fl: features 2fl, 2fl+1
    int rs = rowstart[node], cnt = deg[node];
    const unsigned int* h0u = (const unsigned int*)h0s;
    float accLo = 0.0f, accHi = 0.0f;
    int base = 0;
    for (; base + 8 <= cnt; base += 8) {          // 8 edges in flight (4 per half)
        int i0 = rs + base + half;
        int s0 = csr[i0], s1 = csr[i0 + 2], s2 = csr[i0 + 4], s3 = csr[i0 + 6];
        unsigned int v0 = h0u[(size_t)s0 * 32 + fl];
        unsigned int v1 = h0u[(size_t)s1 * 32 + fl];
        unsigned int v2 = h0u[(size_t)s2 * 32 + fl];
        unsigned int v3 = h0u[(size_t)s3 * 32 + fl];
        accLo += (bfLo(v0) + bfLo(v1)) + (bfLo(v2) + bfLo(v3));
        accHi += (bfHi(v0) + bfHi(v1)) + (bfHi(v2) + bfHi(v3));
    }
    for (int i = base + half; i < cnt; i += 2) {
        unsigned int v = h0u[(size_t)csr[rs + i] * 32 + fl];
        accLo += bfLo(v); accHi += bfHi(v);
    }
    accLo += __shfl_xor(accLo, 32, 64);
    accHi += __shfl_xor(accHi, 32, 64);
    if (half == 0) {
        unsigned int sv = h0u[(size_t)node * 32 + fl];    // self loop
        accLo += bfLo(sv); accHi += bfHi(sv);
        float dv = dinv[node];
        float a1v = alpha1[0];
        float2 r = *(const float2*)&r1h[(size_t)node * 64 + fl * 2];
        float vLo = dv * accLo + b1[fl * 2];
        float vHi = dv * accHi + b1[fl * 2 + 1];
        float2 o = make_float2(silu_f(vLo) + r.x * a1v, silu_f(vHi) + r.y * a1v);
        *(float2*)&r1h[(size_t)node * 64 + fl * 2] = o;
    }
}

// h2s(bf16) = (h @ W2) * dinv ; r2 = silu(h @ Wr2 + br2)
extern "C" __global__ __launch_bounds__(256) void k_gemm2(
    const float* __restrict__ h, const float* __restrict__ W2, const float* __restrict__ Wr2,
    const float* __restrict__ br2, const float* __restrict__ dinv,
    unsigned short* __restrict__ h2s, float* __restrict__ r2, int n)
{
    __shared__ float xsT[64 * 132];
    __shared__ float wsm[64 * 32];
    int t = threadIdx.x;
    int r0 = blockIdx.x * 128;
    int rg = t >> 3;
    int cg = t & 7;
    float acc[4][4] = {};

    #pragma unroll
    for (int i = 0; i < 8; i++) {
        int u = t + i * 256;
        int row = u >> 4, kq = u & 15;
        float4 v = make_float4(0.f, 0.f, 0.f, 0.f);
        int grow = r0 + row;
        if (grow < n) v = *(const float4*)&h[(size_t)grow * 64 + kq * 4];
        xsT[(kq * 4 + 0) * 132 + row] = v.x;
        xsT[(kq * 4 + 1) * 132 + row] = v.y;
        xsT[(kq * 4 + 2) * 132 + row] = v.z;
        xsT[(kq * 4 + 3) * 132 + row] = v.w;
    }
    #pragma unroll
    for (int i = 0; i < 2; i++) {
        int ul = t + i * 256;
        int k = ul >> 3, u = ul & 7;
        int c = u * 4;
        float4 v;
        if (c < 16) v = *(const float4*)&W2[(size_t)k * 16 + c];
        else        v = *(const float4*)&Wr2[(size_t)k * 16 + (c - 16)];
        *(float4*)&wsm[k * 32 + c] = v;
    }
    __syncthreads();

    const float* xbase = &xsT[rg * 4];
    const float* wbase = &wsm[cg * 4];
    #pragma unroll
    for (int k = 0; k < 64; k++) {
        float4 xa = *(const float4*)&xbase[k * 132];
        float4 wa = *(const float4*)&wbase[k * 32];
        float xv[4] = {xa.x, xa.y, xa.z, xa.w};
        float wv[4] = {wa.x, wa.y, wa.z, wa.w};
        #pragma unroll
        for (int i = 0; i < 4; i++)
            #pragma unroll
            for (int j = 0; j < 4; j++) acc[i][j] += xv[i] * wv[j];
    }

    if (cg < 4) {                         // h2s (bf16) cols cg*4..+3
        int c0 = cg * 4;
        #pragma unroll
        for (int i = 0; i < 4; i++) {
            int row = r0 + rg * 4 + i;
            if (row >= n) break;
            float dv = dinv[row];
            unsigned int w0 = f2bf(acc[i][0]*dv) | ((unsigned int)f2bf(acc[i][1]*dv) << 16);
            unsigned int w1 = f2bf(acc[i][2]*dv) | ((unsigned int)f2bf(acc[i][3]*dv) << 16);
            uint2 o = make_uint2(w0, w1);
            *(uint2*)&h2s[(size_t)row * 16 + c0] = o;
        }
    } else {                              // r2 cols 0..15 (f32)
        int c0 = (cg - 4) * 4;
        float4 b = *(const float4*)&br2[c0];
        #pragma unroll
        for (int i = 0; i < 4; i++) {
            int row = r0 + rg * 4 + i;
            if (row >= n) break;
            float4 o = make_float4(silu_f(acc[i][0]+b.x), silu_f(acc[i][1]+b.y),
                                   silu_f(acc[i][2]+b.z), silu_f(acc[i][3]+b.w));
            *(float4*)&r2[(size_t)row * 16 + c0] = o;
        }
    }
}

// z = dinv[dst]*(sum h2s + h2s[dst]) + b2 + r2*alpha2 ; in place over r2.
// Lane = (edge-group, feature-pair): u32 loads, 8 edges per VMEM instr.
extern "C" __global__ __launch_bounds__(256) void k_agg2(
    const unsigned short* __restrict__ h2s, const int* __restrict__ rowstart,
    const int* __restrict__ deg, const int* __restrict__ csr,
    const float* __restrict__ dinv, const float* __restrict__ b2,
    const float* __restrict__ alpha2, float* __restrict__ r2z, int n)
{
    int wave = threadIdx.x >> 6, lane = threadIdx.x & 63;
    int node = blockIdx.x * 4 + wave;
    if (node >= n) return;
    int epg = lane >> 3, fl = lane & 7;            // fl: features 2fl, 2fl+1
    int rs = rowstart[node], cnt = deg[node];
    const unsigned int* h2u = (const unsigned int*)h2s;
    float accLo = 0.0f, accHi = 0.0f;
    int base = 0;
    for (; base + 16 <= cnt; base += 16) {         // 16 edges in flight (2 per group)
        int i0 = rs + base + epg;
        int sa = csr[i0], sb = csr[i0 + 8];
        unsigned int va = h2u[(size_t)sa * 8 + fl];
        unsigned int vb = h2u[(size_t)sb * 8 + fl];
        accLo += bfLo(va) + bfLo(vb);
        accHi += bfHi(va) + bfHi(vb);
    }
    for (int i = base + epg; i < cnt; i += 8) {
        unsigned int v = h2u[(size_t)csr[rs + i] * 8 + fl];
        accLo += bfLo(v); accHi += bfHi(v);
    }
    accLo += __shfl_xor(accLo, 8, 64);  accHi += __shfl_xor(accHi, 8, 64);
    accLo += __shfl_xor(accLo, 16, 64); accHi += __shfl_xor(accHi, 16, 64);
    accLo += __shfl_xor(accLo, 32, 64); accHi += __shfl_xor(accHi, 32, 64);
    if (epg == 0) {
        unsigned int sv = h2u[(size_t)node * 8 + fl];     // self loop
        accLo += bfLo(sv); accHi += bfHi(sv);
        float dv = dinv[node];
        float a2v = alpha2[0];
        float2 r = *(const float2*)&r2z[(size_t)node * 16 + fl * 2];
        float2 o = make_float2(dv * accLo + b2[fl * 2]     + r.x * a2v,
                               dv * accHi + b2[fl * 2 + 1] + r.y * a2v);
        *(float2*)&r2z[(size_t)node * 16 + fl * 2] = o;
    }
}

// fused pool + metrics MLP + classifier head; one block per graph
extern "C" __global__ __launch_bounds__(256) void k_poolhead(
    const float* __restrict__ z, const int* __restrict__ batch,
    const float* __restrict__ tol, const float* __restrict__ cost,
    const float* __restrict__ time_, const float* __restrict__ qty,
    const float* __restrict__ mW1, const float* __restrict__ mb1,
    const float* __restrict__ mW2, const float* __restrict__ mb2,
    const float* __restrict__ Wf1, const float* __restrict__ bf1,
    const float* __restrict__ Wf2, const float* __restrict__ bf2,
    float* __restrict__ out, int n, int NC)
{
    int g = blockIdx.x;
    __shared__ float comb[80];
    __shared__ float part[16][17];
    __shared__ float hidden[80];
    int t = threadIdx.x;

    int lo = 0, hi = n;
    while (lo < hi) { int m = (lo + hi) >> 1; if (batch[m] < g) lo = m + 1; else hi = m; }
    int start = lo;
    lo = start; hi = n;
    while (lo < hi) { int m = (lo + hi) >> 1; if (batch[m] < g + 1) lo = m + 1; else hi = m; }
    int end = lo;

    int j = t & 15, grp = t >> 4;
    float acc = 0.0f;
    for (int r = start + grp; r < end; r += 16) acc += z[(size_t)r * 16 + j];
    part[grp][j] = acc;
    __syncthreads();
    if (t < 16) {
        float s = 0.0f;
        #pragma unroll
        for (int q = 0; q < 16; q++) s += part[q][t];
        comb[t] = s / fmaxf((float)(end - start), 1.0f);
    } else if (t >= 64 && t < 128) {
        int tt = t - 64;
        int i = tt >> 4, jj = tt & 15;
        float mv = (i == 0) ? tol[0] : (i == 1) ? cost[0] : (i == 2) ? time_[0] : qty[0];
        float a = mb2[i * 16 + jj];
        #pragma unroll
        for (int k = 0; k < 8; k++) {
            float hpre = mv * mW1[i * 8 + k] + mb1[i * 8 + k];
            a += silu_f(hpre) * mW2[i * 128 + k * 16 + jj];
        }
        comb[16 + tt] = a;
    }
    __syncthreads();
    if (t < 80) {
        float a = bf1[t];
        #pragma unroll 8
        for (int k = 0; k < 80; k++) a += comb[k] * Wf1[k * 80 + t];
        hidden[t] = silu_f(a);
    }
    __syncthreads();
    if (t < NC) {
        float a = bf2[t];
        #pragma unroll 8
        for (int k = 0; k < 80; k++) a += hidden[k] * Wf2[k * NC + t];
        out[g * NC + t] = a;
    }
}

extern "C" void kernel_launch(void* const* d_in, const int* in_sizes, int n_in,
                              void* d_out, int out_size, void* d_ws, size_t ws_size,
                              hipStream_t stream)
{
    const float* x     = (const float*)d_in[0];
    const int*   ei    = (const int*)d_in[1];
    const int*   batch = (const int*)d_in[2];
    const float* tol   = (const float*)d_in[3];
    const float* cost  = (const float*)d_in[4];
    const float* time_ = (const float*)d_in[5];
    const float* qty   = (const float*)d_in[6];
    const float* W1    = (const float*)d_in[7];
    const float* b1    = (const float*)d_in[8];
    const float* W2    = (const float*)d_in[9];
    const float* b2    = (const float*)d_in[10];
    const float* Wr1   = (const float*)d_in[11];
    const float* br1   = (const float*)d_in[12];
    const float* Wr2   = (const float*)d_in[13];
    const float* br2   = (const float*)d_in[14];
    const float* alpha1= (const float*)d_in[15];
    const float* alpha2= (const float*)d_in[16];
    const float* mW1   = (const float*)d_in[17];
    const float* mb1   = (const float*)d_in[18];
    const float* mW2   = (const float*)d_in[19];
    const float* mb2   = (const float*)d_in[20];
    const float* Wf1   = (const float*)d_in[21];
    const float* bf1   = (const float*)d_in[22];
    const float* Wf2   = (const float*)d_in[23];
    const float* bf2   = (const float*)d_in[24];

    const int N  = in_sizes[2];
    const int E  = in_sizes[1] / 2;
    const int NC = in_sizes[24];
    const int G  = out_size / NC;

    const int* srcIdx = ei;
    const int* dstIdx = ei + E;

    int shift = 8;
    while (((N + (1 << shift) - 1) >> shift) > 512) shift++;
    const int nbkt = (N + (1 << shift) - 1) >> shift;

    char* w = (char*)d_ws;
    auto alloc = [&](size_t bytes) { char* p = w; w += (bytes + 255) & ~(size_t)255; return p; };
    int*   deg      = (int*)alloc((size_t)N * 4);
    int*   rowstart = (int*)alloc((size_t)N * 4);
    int*   bcount   = (int*)alloc(2048);
    int*   boff     = (int*)alloc(2052 + 252);
    int*   bcursor  = (int*)alloc(2048);
    int*   csr      = (int*)alloc((size_t)E * 4);
    int2*  ebuf     = (int2*)alloc((size_t)E * 8);
    float* dinv     = (float*)alloc((size_t)N * 4);
    unsigned short* h0sb = (unsigned short*)alloc((size_t)N * 64 * 2);  // bf16 gather table
    unsigned short* h2sb = (unsigned short*)alloc((size_t)N * 16 * 2);  // bf16 gather table (agg2)
    float* bufB     = (float*)alloc((size_t)N * 64 * 4);  // r1, later h (in place)
    float* bufC     = (float*)alloc((size_t)N * 16 * 4);  // r2, later z (in place)

    hipMemsetAsync(bcount, 0, 2048, stream);

    int EB8 = (E + 8191) / 8192;

    k_bhist   <<<EB8, 256, 0, stream>>>(dstIdx, bcount, E, nbkt, shift);
    k_bscan   <<<1, 512, 0, stream>>>(bcount, boff, bcursor, nbkt);
    k_bscatter<<<EB8, 256, 0, stream>>>(srcIdx, dstIdx, bcursor, ebuf, E, nbkt, shift);
    k_bcsr    <<<nbkt, 256, 0, stream>>>(ebuf, boff, deg, dinv, rowstart, csr, shift, N);

    k_gemm1<<<(N + 127) / 128, 512, 0, stream>>>(x, W1, Wr1, br1, dinv, h0sb, bufB, N);
    k_agg1 <<<(N + 3) / 4, 256, 0, stream>>>(h0sb, rowstart, deg, csr, dinv, b1, alpha1, bufB, N);
    k_gemm2<<<(N + 127) / 128, 256, 0, stream>>>(bufB, W2, Wr2, br2, dinv, h2sb, bufC, N);
    k_agg2 <<<(N + 3) / 4, 256, 0, stream>>>(h2sb, rowstart, deg, csr, dinv, b2, alpha2, bufC, N);
    k_poolhead<<<G, 256, 0, stream>>>(bufC, batch, tol, cost, time_, qty,
                                      mW1, mb1, mW2, mb2, Wf1, bf1, Wf2, bf2,
                                      (float*)d_out, N, NC);
}